// Round 9
// baseline (1617.666 us; speedup 1.0000x reference)
//
#include <hip/hip_runtime.h>
#include <hip/hip_bf16.h>
#include <cstdint>

#define NB 64        // batch
#define ND 64        // DIM
#define NH 8         // heads
#define NTOK 226
#define NSB 128      // 2*B (both streams batched)
#define NROWS (NSB*NTOK)   // 28928

#define XTP 240      // global XnT pitch (u16), cols 226..239 zeroed
#define PWP 40       // per-wave E-staging pitch (u16)

typedef __attribute__((ext_vector_type(8))) short bfrag8;
typedef __attribute__((ext_vector_type(4))) float ffrag4;

// RNE bf16 (bit-exact vs __float2bfloat16 for finite values; 3 VALU ops)
__device__ __forceinline__ unsigned short f2b(float f) {
  uint32_t u; __builtin_memcpy(&u, &f, 4);
  u += 0x7fff + ((u >> 16) & 1);
  return (unsigned short)(u >> 16);
}

// ---- fusion-matrix diagonal: sdfm[b][d] = sqrt(sigmoid(x @ fmg_w[:,65d])) ----
__global__ void k_dfm(const float* __restrict__ hsi, const float* __restrict__ lidar,
                      const float* __restrict__ fmg_w, float* __restrict__ sdfm) {
  __shared__ float xc[128];
  int b = blockIdx.x, t = threadIdx.x;
  const float* src = (t < 64) ? hsi : lidar;
  int d = t & 63;
  const float* p = src + ((size_t)b * 64 + d) * 225;
  float s = 0.f;
  for (int i = 0; i < 225; ++i) s += p[i];
  xc[t] = s * (1.0f / 225.0f);
  __syncthreads();
  if (t < 64) {
    float acc = 0.f;
    const float* w = fmg_w + t * 65;       // column 65*t of [128,4096]
    for (int c = 0; c < 128; ++c) acc += xc[c] * w[c * 4096];
    float sg = 1.0f / (1.0f + expf(-acc));
    sdfm[b * 64 + t] = sqrtf(sg);
  }
}

// ---- build X[2B,226,64] (+ pos) and Xn = LN1_0(X); one wave per row ----
__global__ void k_build(const float* __restrict__ hsi,
                        const float* __restrict__ cls_h, const float* __restrict__ cls_l,
                        const float* __restrict__ pos_h, const float* __restrict__ pos_l,
                        const float* __restrict__ g, const float* __restrict__ bb,
                        float* __restrict__ X, uint16_t* __restrict__ Xn) {
  int r = blockIdx.x;                 // sb*226 + n
  int sb = r / NTOK, n = r - sb * NTOK;
  int s = sb >> 6, b = sb & 63;
  int d = threadIdx.x;                // 64 threads = 1 wave
  float v;
  if (n == 0) v = s ? cls_l[d] : cls_h[d];
  else        v = hsi[((size_t)b * 64 + d) * 225 + (n - 1)];
  v += (s ? pos_l : pos_h)[n * ND + d];
  X[(size_t)r * ND + d] = v;
  float sm = v, sq = v * v;
  #pragma unroll
  for (int o = 32; o; o >>= 1) { sm += __shfl_xor(sm, o); sq += __shfl_xor(sq, o); }
  float m = sm * (1.f / 64.f);
  float rs = rsqrtf(sq * (1.f / 64.f) - m * m + 1e-5f);
  Xn[(size_t)r * ND + d] = f2b((v - m) * rs * g[d] + bb[d]);
}

// ---- FF weight convert to bf16 [col][k] layouts ----
__global__ __launch_bounds__(256) void k_wconv2(
    const float* __restrict__ ff_w1, const float* __restrict__ ff_w2,
    uint16_t* __restrict__ W1, uint16_t* __restrict__ W2) {
  int i = blockIdx.x * 256 + threadIdx.x;   // 131072
  if (i < 65536) {
    int ly = i >> 14, rem = i & 16383, n = rem >> 6, k = rem & 63;
    W1[i] = f2b(ff_w1[((size_t)ly * 64 + k) * 256 + n]);
  } else {
    int j = i - 65536;
    int ly = j >> 14, rem = j & 16383, n = rem >> 8, k = rem & 255;
    W2[j] = f2b(ff_w2[((size_t)ly * 256 + k) * 64 + n]);
  }
}

// ---- Gp[ly][n][h*64+d] = (Wv_h · Wo_h)[d][n]: fused V->proj weight, [n][k] ----
__global__ __launch_bounds__(256) void k_gconv(const float* __restrict__ qkv_w,
    const float* __restrict__ out_w, uint16_t* __restrict__ Gp) {
  int idx = blockIdx.x * 256 + threadIdx.x;   // 131072
  int ly = idx >> 15, h = (idx >> 12) & 7, d = (idx >> 6) & 63, n = idx & 63;
  const float* qp = qkv_w + ((size_t)(ly * 64 + d)) * 1536 + 1024 + h * 64;
  const float* op = out_w + ((size_t)(ly * 512 + h * 64)) * 64 + n;
  float acc = 0.f;
  for (int dh = 0; dh < 64; ++dh) acc += qp[dh] * op[(size_t)dh * 64];
  Gp[(size_t)(ly * 64 + n) * 512 + h * 64 + d] = f2b(acc);
}

// ---- Mt[ly][b][h][64][64] = Wq_h diag(dfm_b/8) Wq_h^T (symmetric) ----
__global__ void k_mconv(const float* __restrict__ qkv_w,
    const float* __restrict__ sdfm, uint16_t* __restrict__ Mt) {
  __shared__ __align__(16) uint16_t ws[64 * 64];   // 8 KB
  int bx = blockIdx.x;                       // (ly, b, h)
  int ly = bx >> 9, b = (bx >> 3) & 63, h = bx & 7;
  int t = threadIdx.x;                       // 64 threads = 1 wave
  float sf = sdfm[b * 64 + t] * 0.35355339059327373f;   // sqrt(1/8)
  for (int k = 0; k < 64; ++k) {
    float wv = qkv_w[((size_t)(ly * 64 + k)) * 1536 + h * 64 + t];
    ws[k * 64 + (((t >> 3) ^ (k & 7)) << 3) + (t & 7)] = f2b(wv * sf);
  }
  __syncthreads();
  int quad = t >> 4, c = t & 15;
  uint16_t* out = Mt + ((size_t)bx << 12);
  for (int it = 0; it < 4; ++it) {
    int ra = it * 16 + c, sa = ra & 7;
    bfrag8 a0 = *(const bfrag8*)(ws + ra * 64 + ((quad ^ sa) << 3));
    bfrag8 a1 = *(const bfrag8*)(ws + ra * 64 + (((quad + 4) ^ sa) << 3));
    for (int jt = 0; jt < 4; ++jt) {
      int rb = jt * 16 + c, sk = rb & 7;
      bfrag8 b0 = *(const bfrag8*)(ws + rb * 64 + ((quad ^ sk) << 3));
      bfrag8 b1 = *(const bfrag8*)(ws + rb * 64 + (((quad + 4) ^ sk) << 3));
      ffrag4 z = {0.f, 0.f, 0.f, 0.f};
      z = __builtin_amdgcn_mfma_f32_16x16x32_bf16(a0, b0, z, 0, 0, 0);
      z = __builtin_amdgcn_mfma_f32_16x16x32_bf16(a1, b1, z, 0, 0, 0);
      #pragma unroll
      for (int r = 0; r < 4; ++r)
        out[(it * 16 + quad * 4 + r) * 64 + jt * 16 + c] = f2b(z[r]);
    }
  }
}

// ---- T = Xn · Mcat (per sb), plus global XnT emission (identity-MFMA transpose) ----
// Grid 512 = sb*4 + qq; 4 waves; wave handles i-tile it = qq*4+w (16-row strip).
__global__ __launch_bounds__(256) void k_tq(const uint16_t* __restrict__ Xn,
    const uint16_t* __restrict__ Mt,    // layer base [64 b][512 n][64 k]
    uint16_t* __restrict__ Tg, uint16_t* __restrict__ XnT) {
  int bx = blockIdx.x, sb = bx >> 2, qq = bx & 3;
  int t = threadIdx.x, w = t >> 6, l = t & 63, quad = l >> 4, c = l & 15;
  const uint16_t* Xb = Xn + (size_t)sb * NTOK * ND;
  const uint16_t* Mb = Mt + ((size_t)(sb & 63) << 15);   // *512*64
  uint16_t* XnTb = XnT + (size_t)sb * 64 * XTP;
  int it = qq * 4 + w;                 // 0..15 (it 15: pad strip, stores guarded)
  int i0 = it * 16;
  int ric = i0 + c; if (ric > 225) ric = 225;
  bfrag8 a0 = *(const bfrag8*)(Xb + (size_t)ric * 64 + quad * 8);
  bfrag8 a1 = *(const bfrag8*)(Xb + (size_t)ric * 64 + 32 + quad * 8);

  // XnT strip via identity-MFMA transpose (R8-validated)
  #pragma unroll
  for (int dt = 0; dt < 4; ++dt) {
    int pos = dt * 16 + c;
    union { short s[8]; bfrag8 v; } u0, u1;
    #pragma unroll
    for (int e = 0; e < 8; ++e) {
      u0.s[e] = (pos < 32 && (pos >> 3) == quad && (pos & 7) == e) ? (short)0x3F80 : (short)0;
      u1.s[e] = (pos >= 32 && ((pos - 32) >> 3) == quad && (pos & 7) == e) ? (short)0x3F80 : (short)0;
    }
    ffrag4 z = {0.f, 0.f, 0.f, 0.f};
    z = __builtin_amdgcn_mfma_f32_16x16x32_bf16(u0.v, a0, z, 0, 0, 0);
    z = __builtin_amdgcn_mfma_f32_16x16x32_bf16(u1.v, a1, z, 0, 0, 0);
    if (i0 + c < NTOK) {
      #pragma unroll
      for (int r = 0; r < 4; ++r)
        XnTb[(dt * 16 + quad * 4 + r) * XTP + i0 + c] = f2b(z[r]);
    }
  }
  // zero XnT pad cols 226..239 (once, from qq==3 blocks)
  if (qq == 3) {
    for (int idx = t; idx < 64 * 7; idx += 256) {
      int d = idx / 7, cc = 226 + 2 * (idx % 7);
      *(uint32_t*)(XnTb + d * XTP + cc) = 0;
    }
  }
  // T GEMM: cols in 4 chunks of 128
  for (int cg = 0; cg < 4; ++cg) {
    ffrag4 acc[8];
    #pragma unroll
    for (int ct = 0; ct < 8; ++ct) acc[ct] = (ffrag4){0.f, 0.f, 0.f, 0.f};
    #pragma unroll
    for (int ct = 0; ct < 8; ++ct) {
      int n = cg * 128 + ct * 16 + c;
      bfrag8 b0 = *(const bfrag8*)(Mb + (size_t)n * 64 + quad * 8);
      bfrag8 b1 = *(const bfrag8*)(Mb + (size_t)n * 64 + 32 + quad * 8);
      acc[ct] = __builtin_amdgcn_mfma_f32_16x16x32_bf16(a0, b0, acc[ct], 0, 0, 0);
      acc[ct] = __builtin_amdgcn_mfma_f32_16x16x32_bf16(a1, b1, acc[ct], 0, 0, 0);
    }
    #pragma unroll
    for (int ct = 0; ct < 8; ++ct) {
      #pragma unroll
      for (int r = 0; r < 4; ++r) {
        int i = i0 + quad * 4 + r;
        if (i < NTOK)
          Tg[((size_t)sb * NTOK + i) * 512 + cg * 128 + ct * 16 + c] = f2b(acc[ct][r]);
      }
    }
  }
}

// ---- attention core: S = T_h·Xn^T, softmax, U = E·Xn; all operands global ----
// Grid 4096 = ((sb*8+h)*4+qq); one i-tile per wave; no barriers; LDS 5 KB.
__global__ __launch_bounds__(256) void k_sattn(const uint16_t* __restrict__ Tg,
    const uint16_t* __restrict__ Xn, const uint16_t* __restrict__ XnT,
    uint16_t* __restrict__ Og) {
  __shared__ __align__(16) uint16_t pwb[4][16 * PWP];   // 5120 B
  int bx = blockIdx.x, sb = bx >> 5, h = (bx >> 2) & 7, qq = bx & 3;
  int t = threadIdx.x, w = t >> 6, l = t & 63, quad = l >> 4, c = l & 15;
  int it = qq * 4 + w;
  if (it > 14) return;                 // wave-uniform, no barriers in kernel
  int i0 = it * 16;
  const uint16_t* Xb = Xn + (size_t)sb * NTOK * ND;
  const uint16_t* XnTb = XnT + (size_t)sb * 64 * XTP;
  uint16_t* pw = &pwb[w][0];

  int ric = i0 + c; if (ric > 225) ric = 225;
  const uint16_t* trow = Tg + ((size_t)sb * NTOK + ric) * 512 + h * 64;
  bfrag8 aT0 = *(const bfrag8*)(trow + quad * 8);
  bfrag8 aT1 = *(const bfrag8*)(trow + 32 + quad * 8);

  // S strip = T_h · Xn^T  (B = global Xn rows, [j][k])
  ffrag4 sacc[15];
  #pragma unroll
  for (int jt = 0; jt < 15; ++jt) {
    int rj = jt * 16 + c; if (rj > 225) rj = 225;
    bfrag8 b0 = *(const bfrag8*)(Xb + (size_t)rj * 64 + quad * 8);
    bfrag8 b1 = *(const bfrag8*)(Xb + (size_t)rj * 64 + 32 + quad * 8);
    ffrag4 z = {0.f, 0.f, 0.f, 0.f};
    z = __builtin_amdgcn_mfma_f32_16x16x32_bf16(aT0, b0, z, 0, 0, 0);
    z = __builtin_amdgcn_mfma_f32_16x16x32_bf16(aT1, b1, z, 0, 0, 0);
    sacc[jt] = z;
  }
  // softmax (raw E kept; 1/l at store)
  float rinv[4];
  #pragma unroll
  for (int r = 0; r < 4; ++r) {
    float m = -1e30f;
    #pragma unroll
    for (int jt = 0; jt < 15; ++jt) m = fmaxf(m, sacc[jt][r]);
    #pragma unroll
    for (int o = 8; o; o >>= 1) m = fmaxf(m, __shfl_xor(m, o));
    float s = 0.f;
    #pragma unroll
    for (int jt = 0; jt < 15; ++jt) {
      float p = __expf(sacc[jt][r] - m);
      if (jt == 14 && c >= 2) p = 0.f;   // j = 224+c >= 226 (dup rows) masked
      sacc[jt][r] = p;
      s += p;
    }
    #pragma unroll
    for (int o = 8; o; o >>= 1) s += __shfl_xor(s, o);
    rinv[r] = 1.f / s;
  }
  // U = E · Xn  (A: E via per-wave LDS; B: global XnT rows, [d][j])
  ffrag4 uacc[4];
  #pragma unroll
  for (int dt = 0; dt < 4; ++dt) uacc[dt] = (ffrag4){0.f, 0.f, 0.f, 0.f};
  #pragma unroll
  for (int jc = 0; jc < 8; ++jc) {
    if (jc == 7)
      *(uint64_t*)(pw + c * PWP + 16 + quad * 4) = 0ull;   // zero E cols 16..31
    #pragma unroll
    for (int r = 0; r < 4; ++r) {
      int row = quad * 4 + r;
      pw[row * PWP + c] = f2b(sacc[2 * jc][r]);
      if (jc < 7) pw[row * PWP + 16 + c] = f2b(sacc[2 * jc + 1][r]);
    }
    bfrag8 pa = *(const bfrag8*)(pw + c * PWP + quad * 8);
    int jb = (jc < 7) ? (jc * 32 + quad * 8) : 224;   // tail: E=0 beyond j=225
    #pragma unroll
    for (int dt = 0; dt < 4; ++dt) {
      bfrag8 vb = *(const bfrag8*)(XnTb + (dt * 16 + c) * XTP + jb);
      uacc[dt] = __builtin_amdgcn_mfma_f32_16x16x32_bf16(pa, vb, uacc[dt], 0, 0, 0);
    }
  }
  // store normalized U into Og (k_proj applies G = Wv·Wo)
  #pragma unroll
  for (int dt = 0; dt < 4; ++dt) {
    #pragma unroll
    for (int r = 0; r < 4; ++r) {
      int i = i0 + quad * 4 + r;
      if (i < NTOK)
        Og[((size_t)sb * NTOK + i) * 512 + h * 64 + dt * 16 + c] =
            f2b(uacc[dt][r] * rinv[r]);
    }
  }
}

// ---- MFMA out-projection (U·G) + residual + LN2 emission ----
__global__ __launch_bounds__(256) void k_proj(const uint16_t* __restrict__ Og,
    const uint16_t* __restrict__ Gp,    // [64][512] bf16 (this layer)
    const float* __restrict__ bo, float* __restrict__ X,
    const float* __restrict__ g2, const float* __restrict__ bb2,
    uint16_t* __restrict__ Xn2) {
  int t = threadIdx.x, w = t >> 6, l = t & 63;
  int quad = l >> 4, c = l & 15;
  int r0 = blockIdx.x * 64;
  const uint16_t* orow = Og + (size_t)(r0 + w * 16 + c) * 512 + quad * 8;
  bfrag8 a[16];
  #pragma unroll
  for (int kc = 0; kc < 16; ++kc) a[kc] = *(const bfrag8*)(orow + kc * 32);
  ffrag4 acc[4];
  #pragma unroll
  for (int jt = 0; jt < 4; ++jt) acc[jt] = (ffrag4){0.f, 0.f, 0.f, 0.f};
  #pragma unroll
  for (int kc = 0; kc < 16; ++kc) {
    #pragma unroll
    for (int jt = 0; jt < 4; ++jt) {
      bfrag8 b = *(const bfrag8*)(Gp + (size_t)(jt * 16 + c) * 512 + kc * 32 + quad * 8);
      acc[jt] = __builtin_amdgcn_mfma_f32_16x16x32_bf16(a[kc], b, acc[jt], 0, 0, 0);
    }
  }
  float xv[4][4];
  #pragma unroll
  for (int jt = 0; jt < 4; ++jt) {
    float bv = bo[jt * 16 + c];
    #pragma unroll
    for (int r = 0; r < 4; ++r) {
      int il = w * 16 + quad * 4 + r;
      size_t idx = (size_t)(r0 + il) * 64 + jt * 16 + c;
      float v = X[idx] + acc[jt][r] + bv;
      X[idx] = v;
      xv[jt][r] = v;
    }
  }
  #pragma unroll
  for (int r = 0; r < 4; ++r) {
    float s = xv[0][r] + xv[1][r] + xv[2][r] + xv[3][r];
    float q = xv[0][r]*xv[0][r] + xv[1][r]*xv[1][r] + xv[2][r]*xv[2][r] + xv[3][r]*xv[3][r];
    #pragma unroll
    for (int o = 8; o; o >>= 1) { s += __shfl_xor(s, o); q += __shfl_xor(q, o); }
    float m = s * (1.f / 64.f);
    float rs = rsqrtf(q * (1.f / 64.f) - m * m + 1e-5f);
    int il = w * 16 + quad * 4 + r;
    #pragma unroll
    for (int jt = 0; jt < 4; ++jt) {
      int n = jt * 16 + c;
      Xn2[(size_t)(r0 + il) * 64 + n] = f2b((xv[jt][r] - m) * rs * g2[n] + bb2[n]);
    }
  }
}

// ---- MFMA FF (A-frags from global Xn2) + residual + next-layer LN1 emission ----
__global__ __launch_bounds__(256) void k_ff(float* __restrict__ X,
    const uint16_t* __restrict__ Xn2,
    const uint16_t* __restrict__ W1t,   // [256][64] bf16
    const float* __restrict__ b1,
    const uint16_t* __restrict__ W2t,   // [64][256] bf16
    const float* __restrict__ b2,
    const float* __restrict__ gn, const float* __restrict__ bbn,
    uint16_t* __restrict__ XnOut) {
  __shared__ __align__(16) uint16_t ha[4][16 * 264];   // 33792 B, per-wave h-tile
  int t = threadIdx.x, w = t >> 6, l = t & 63;
  int quad = l >> 4, c = l & 15;
  int r0 = blockIdx.x * 64;
  const uint16_t* xrow = Xn2 + (size_t)(r0 + w * 16 + c) * 64;
  bfrag8 a0 = *(const bfrag8*)(xrow + quad * 8);
  bfrag8 a1 = *(const bfrag8*)(xrow + 32 + quad * 8);
  ffrag4 acc[16];
  #pragma unroll
  for (int jt = 0; jt < 16; ++jt) {
    bfrag8 b0  = *(const bfrag8*)(W1t + (size_t)(jt * 16 + c) * 64 + quad * 8);
    bfrag8 b1f = *(const bfrag8*)(W1t + (size_t)(jt * 16 + c) * 64 + 32 + quad * 8);
    ffrag4 z = {0.f, 0.f, 0.f, 0.f};
    z = __builtin_amdgcn_mfma_f32_16x16x32_bf16(a0, b0, z, 0, 0, 0);
    z = __builtin_amdgcn_mfma_f32_16x16x32_bf16(a1, b1f, z, 0, 0, 0);
    acc[jt] = z;
  }
  uint16_t* haw = &ha[w][0];
  #pragma unroll
  for (int jt = 0; jt < 16; ++jt) {
    float bv = b1[jt * 16 + c];
    #pragma unroll
    for (int r = 0; r < 4; ++r) {
      float z = acc[jt][r] + bv;
      float hg = 0.5f * z * (1.f + erff(z * 0.7071067811865476f));
      haw[(quad * 4 + r) * 264 + jt * 16 + c] = f2b(hg);
    }
  }
  __syncthreads();
  ffrag4 o2[4];
  #pragma unroll
  for (int jt = 0; jt < 4; ++jt) o2[jt] = (ffrag4){0.f, 0.f, 0.f, 0.f};
  #pragma unroll
  for (int kc = 0; kc < 8; ++kc) {
    bfrag8 pa = *(const bfrag8*)(haw + c * 264 + kc * 32 + quad * 8);
    #pragma unroll
    for (int jt = 0; jt < 4; ++jt) {
      bfrag8 vb = *(const bfrag8*)(W2t + (size_t)(jt * 16 + c) * 256 + kc * 32 + quad * 8);
      o2[jt] = __builtin_amdgcn_mfma_f32_16x16x32_bf16(pa, vb, o2[jt], 0, 0, 0);
    }
  }
  float xv[4][4];
  #pragma unroll
  for (int jt = 0; jt < 4; ++jt) {
    float bv = b2[jt * 16 + c];
    #pragma unroll
    for (int r = 0; r < 4; ++r) {
      int il = w * 16 + quad * 4 + r;
      size_t idx = (size_t)(r0 + il) * 64 + jt * 16 + c;
      float v = X[idx] + o2[jt][r] + bv;
      X[idx] = v;
      xv[jt][r] = v;
    }
  }
  #pragma unroll
  for (int r = 0; r < 4; ++r) {
    float s = xv[0][r] + xv[1][r] + xv[2][r] + xv[3][r];
    float q = xv[0][r]*xv[0][r] + xv[1][r]*xv[1][r] + xv[2][r]*xv[2][r] + xv[3][r]*xv[3][r];
    #pragma unroll
    for (int o = 8; o; o >>= 1) { s += __shfl_xor(s, o); q += __shfl_xor(q, o); }
    float m = s * (1.f / 64.f);
    float rs = rsqrtf(q * (1.f / 64.f) - m * m + 1e-5f);
    int il = w * 16 + quad * 4 + r;
    #pragma unroll
    for (int jt = 0; jt < 4; ++jt) {
      int n = jt * 16 + c;
      XnOut[(size_t)(r0 + il) * 64 + n] = f2b((xv[jt][r] - m) * rs * gn[n] + bbn[n]);
    }
  }
}

// ---- swap cls tokens between streams; refresh Xn (LN1 layer0) for those rows ----
__global__ void k_xchg(float* __restrict__ X, uint16_t* __restrict__ Xn,
                       const float* __restrict__ g, const float* __restrict__ bb) {
  int b = blockIdx.x, d = threadIdx.x;   // 64 blocks x 64 threads (1 wave)
  size_t i0 = (size_t)(b * NTOK) * ND + d;
  size_t i1 = (size_t)((64 + b) * NTOK) * ND + d;
  float a = X[i0], cc = X[i1];
  X[i0] = cc; X[i1] = a;
  float s0 = cc, q0 = cc * cc, s1 = a, q1 = a * a;
  #pragma unroll
  for (int o = 32; o; o >>= 1) {
    s0 += __shfl_xor(s0, o); q0 += __shfl_xor(q0, o);
    s1 += __shfl_xor(s1, o); q1 += __shfl_xor(q1, o);
  }
  float m0 = s0 * (1.f / 64.f), rs0 = rsqrtf(q0 * (1.f / 64.f) - m0 * m0 + 1e-5f);
  float m1 = s1 * (1.f / 64.f), rs1 = rsqrtf(q1 * (1.f / 64.f) - m1 * m1 + 1e-5f);
  Xn[i0] = f2b((cc - m0) * rs0 * g[d] + bb[d]);
  Xn[i1] = f2b((a - m1) * rs1 * g[d] + bb[d]);
}

// ---- final: out = h_cls + l_cls ----
__global__ void k_out(const float* __restrict__ X, float* __restrict__ out) {
  int i = blockIdx.x * 64 + threadIdx.x;
  int b = i >> 6, d = i & 63;
  out[i] = X[(size_t)b * NTOK * ND + d] + X[(size_t)(64 + b) * NTOK * ND + d];
}

extern "C" void kernel_launch(void* const* d_in, const int* in_sizes, int n_in,
                              void* d_out, int out_size, void* d_ws, size_t ws_size,
                              hipStream_t stream) {
  const float* hsi   = (const float*)d_in[0];
  const float* lidar = (const float*)d_in[1];
  const float* cls_h = (const float*)d_in[2];
  const float* cls_l = (const float*)d_in[3];
  const float* pos_h = (const float*)d_in[4];
  const float* pos_l = (const float*)d_in[5];
  const float* fmg_w = (const float*)d_in[6];
  const float* ln1_g = (const float*)d_in[7];
  const float* ln1_b = (const float*)d_in[8];
  const float* qkv_w = (const float*)d_in[9];
  const float* out_w = (const float*)d_in[10];
  const float* out_b = (const float*)d_in[11];
  const float* ln2_g = (const float*)d_in[12];
  const float* ln2_b = (const float*)d_in[13];
  const float* ff_w1 = (const float*)d_in[14];
  const float* ff_b1 = (const float*)d_in[15];
  const float* ff_w2 = (const float*)d_in[16];
  const float* ff_b2 = (const float*)d_in[17];

  char* ws = (char*)d_ws;
  float*    X    = (float*)ws;                       // 7,405,568 B
  float*    sdfm = (float*)(ws + 7405568);           // 16,384 B
  uint16_t* Xn   = (uint16_t*)(ws + 7421952);        // 3,702,784 B
  uint16_t* Xn2  = (uint16_t*)(ws + 11124736);       // 3,702,784 B
  uint16_t* Og   = (uint16_t*)(ws + 14827520);       // 29,622,272 B
  uint16_t* Tg   = (uint16_t*)(ws + 44449792);       // 29,622,272 B
  uint16_t* XnT  = (uint16_t*)(ws + 74072064);       // 3,932,160 B
  uint16_t* Mt   = (uint16_t*)(ws + 78004224);       // 16,777,216 B
  uint16_t* Gp   = (uint16_t*)(ws + 94781440);       // 262,144 B
  uint16_t* W1   = (uint16_t*)(ws + 95043584);       // 131,072 B
  uint16_t* W2   = (uint16_t*)(ws + 95174656);       // 131,072 B -> end 95,305,728

  k_wconv2<<<512, 256, 0, stream>>>(ff_w1, ff_w2, W1, W2);
  k_gconv<<<512, 256, 0, stream>>>(qkv_w, out_w, Gp);
  k_dfm<<<NB, 128, 0, stream>>>(hsi, lidar, fmg_w, sdfm);
  k_mconv<<<2048, 64, 0, stream>>>(qkv_w, sdfm, Mt);
  k_build<<<NROWS, 64, 0, stream>>>(hsi, cls_h, cls_l, pos_h, pos_l,
                                    ln1_g, ln1_b, X, Xn);
  for (int pass = 0; pass < 2; ++pass) {
    for (int ly = 0; ly < 4; ++ly) {
      int nx = (ly + 1) & 3;   // next layer's LN1 params (harmless on final layer)
      k_tq<<<512, 256, 0, stream>>>(Xn, Mt + (size_t)ly * 2097152, Tg, XnT);
      k_sattn<<<4096, 256, 0, stream>>>(Tg, Xn, XnT, Og);
      k_proj<<<452, 256, 0, stream>>>(Og, Gp + (size_t)ly * 32768, out_b + ly * ND,
                                      X, ln2_g + ly * ND, ln2_b + ly * ND, Xn2);
      k_ff<<<452, 256, 0, stream>>>(X, Xn2,
                                    W1 + (size_t)ly * 16384, ff_b1 + ly * 256,
                                    W2 + (size_t)ly * 16384, ff_b2 + ly * ND,
                                    ln1_g + nx * ND, ln1_b + nx * ND, Xn);
    }
    if (pass == 0) k_xchg<<<64, 64, 0, stream>>>(X, Xn, ln1_g, ln1_b);
  }
  k_out<<<64, 64, 0, stream>>>(X, (float*)d_out);
}

// Round 10
// 851.411 us; speedup vs baseline: 1.9000x; 1.9000x over previous
//
#include <hip/hip_runtime.h>
#include <hip/hip_bf16.h>
#include <cstdint>

#define NB 64        // batch
#define ND 64        // DIM
#define NH 8         // heads
#define DH 64        // dim_head
#define NIN 512      // inner
#define NMLP 256
#define NDEPTH 4
#define NPATCH 225
#define NTOK 226
#define NSB 128      // 2*B (both streams batched)
#define NROWS (NSB*NTOK)   // 28928

#define VP 240       // attention Vt LDS pitch (bf16 units) — R5-validated

typedef __attribute__((ext_vector_type(8))) short bfrag8;
typedef __attribute__((ext_vector_type(4))) float ffrag4;

// RNE bf16: bit-exact vs __float2bfloat16 for finite inputs, 3 VALU ops.
// (validated: R6-R9 all passed with absmax identical to the slow path)
__device__ __forceinline__ unsigned short f2b(float f) {
  uint32_t u; __builtin_memcpy(&u, &f, 4);
  u += 0x7fff + ((u >> 16) & 1);
  return (unsigned short)(u >> 16);
}

// ---- fusion-matrix diagonal: sdfm[b][d] = sqrt(sigmoid(x @ fmg_w[:,65d])) ----
__global__ void k_dfm(const float* __restrict__ hsi, const float* __restrict__ lidar,
                      const float* __restrict__ fmg_w, float* __restrict__ sdfm) {
  __shared__ float xc[128];
  int b = blockIdx.x, t = threadIdx.x;
  const float* src = (t < 64) ? hsi : lidar;
  int d = t & 63;
  const float* p = src + ((size_t)b * 64 + d) * NPATCH;
  float s = 0.f;
  for (int i = 0; i < NPATCH; ++i) s += p[i];
  xc[t] = s * (1.0f / 225.0f);
  __syncthreads();
  if (t < 64) {
    float acc = 0.f;
    const float* w = fmg_w + t * 65;       // column 65*t of [128,4096]
    for (int c = 0; c < 128; ++c) acc += xc[c] * w[c * 4096];
    float sg = 1.0f / (1.0f + expf(-acc));
    sdfm[b * 64 + t] = sqrtf(sg);
  }
}

// ---- build X[2B,226,64] (+ pos) and Xn = LN1_0(X); one wave per row ----
__global__ void k_build(const float* __restrict__ hsi,
                        const float* __restrict__ cls_h, const float* __restrict__ cls_l,
                        const float* __restrict__ pos_h, const float* __restrict__ pos_l,
                        const float* __restrict__ g, const float* __restrict__ bb,
                        float* __restrict__ X, uint16_t* __restrict__ Xn) {
  int r = blockIdx.x;                 // sb*226 + n
  int sb = r / NTOK, n = r - sb * NTOK;
  int s = sb >> 6, b = sb & 63;
  int d = threadIdx.x;                // 64 threads = 1 wave
  float v;
  if (n == 0) v = s ? cls_l[d] : cls_h[d];
  else        v = hsi[((size_t)b * 64 + d) * NPATCH + (n - 1)];
  v += (s ? pos_l : pos_h)[n * ND + d];
  X[(size_t)r * ND + d] = v;
  float sm = v, sq = v * v;
  #pragma unroll
  for (int o = 32; o; o >>= 1) { sm += __shfl_xor(sm, o); sq += __shfl_xor(sq, o); }
  float m = sm * (1.f / 64.f);
  float rs = rsqrtf(sq * (1.f / 64.f) - m * m + 1e-5f);
  Xn[(size_t)r * ND + d] = f2b((v - m) * rs * g[d] + bb[d]);
}

// ---- weight convert+transpose to bf16 [col][k] layouts, all layers ----
__global__ __launch_bounds__(256) void k_wconv(
    const float* __restrict__ qkv_w, const float* __restrict__ out_w,
    const float* __restrict__ ff_w1, const float* __restrict__ ff_w2,
    uint16_t* __restrict__ Wqv, uint16_t* __restrict__ Wo,
    uint16_t* __restrict__ W1, uint16_t* __restrict__ W2) {
  int i = blockIdx.x * 256 + threadIdx.x;   // grid covers 524288
  if (i < 262144) {
    int ly = i >> 16, rem = i & 65535, n = rem >> 6, k = rem & 63;
    int col = n + ((n >> 9) << 9);          // n<512 ? q col n : v col n+512
    Wqv[i] = f2b(qkv_w[((size_t)ly * 64 + k) * 1536 + col]);
  } else if (i < 393216) {
    int j = i - 262144;
    int ly = j >> 15, rem = j & 32767, n = rem >> 9, k = rem & 511;
    Wo[j] = f2b(out_w[((size_t)ly * 512 + k) * 64 + n]);
  } else if (i < 458752) {
    int j = i - 393216;
    int ly = j >> 14, rem = j & 16383, n = rem >> 6, k = rem & 63;
    W1[j] = f2b(ff_w1[((size_t)ly * 64 + k) * 256 + n]);
  } else {
    int j = i - 458752;
    int ly = j >> 14, rem = j & 16383, n = rem >> 8, k = rem & 255;
    W2[j] = f2b(ff_w2[((size_t)ly * 256 + k) * 64 + n]);
  }
}

// ---- fused QV-projection + MFMA attention (R5 structure, exact) ----
// Phase 1: Q = Xn@Wq (scaled) -> qs (XOR-swizzled, 240 rows incl. dup pads);
//          V = Xn@Wv -> vt transposed (element scatter, even banks).
// Phase 2: S = Qs Qs^T, softmax storing raw E, PV, O *= 1/l at store.
// LDS = 30720 + 30720 + 4096 = 65536 B exactly.
__global__ __launch_bounds__(256) void k_fattn(const uint16_t* __restrict__ Xn,
    const uint16_t* __restrict__ Wqv,   // [1024][64] this layer
    const float* __restrict__ sdfm, uint16_t* __restrict__ Og) {
  __shared__ __align__(16) uint16_t qs[240 * 64];
  __shared__ __align__(16) uint16_t vt[64 * VP];
  __shared__ __align__(16) uint16_t pb[4][512];
  int bh = blockIdx.x;
  int sb = bh >> 3, h = bh & 7;
  int t = threadIdx.x, w = t >> 6, l = t & 63;
  int quad = l >> 4, c = l & 15;
  const uint16_t* Xb = Xn + (size_t)sb * NTOK * ND;

  float sf[4];
  #pragma unroll
  for (int dt = 0; dt < 4; ++dt)
    sf[dt] = sdfm[(sb & 63) * 64 + dt * 16 + c] * 0.35355339059327373f;  // sqrt(1/8)

  // phase 1: Q,V projection for this head
  for (int it = w; it < 15; it += 4) {
    int i0 = it * 16;
    int ri = i0 + c; if (ri > 225) ri = 225;
    bfrag8 a0 = *(const bfrag8*)(Xb + (size_t)ri * 64 + quad * 8);
    bfrag8 a1 = *(const bfrag8*)(Xb + (size_t)ri * 64 + 32 + quad * 8);
    #pragma unroll
    for (int dt = 0; dt < 4; ++dt) {
      int nq = h * 64 + dt * 16 + c;
      bfrag8 bq0 = *(const bfrag8*)(Wqv + (size_t)nq * 64 + quad * 8);
      bfrag8 bq1 = *(const bfrag8*)(Wqv + (size_t)nq * 64 + 32 + quad * 8);
      ffrag4 zq = {0.f, 0.f, 0.f, 0.f};
      zq = __builtin_amdgcn_mfma_f32_16x16x32_bf16(a0, bq0, zq, 0, 0, 0);
      zq = __builtin_amdgcn_mfma_f32_16x16x32_bf16(a1, bq1, zq, 0, 0, 0);
      bfrag8 bv0 = *(const bfrag8*)(Wqv + (size_t)(512 + nq) * 64 + quad * 8);
      bfrag8 bv1 = *(const bfrag8*)(Wqv + (size_t)(512 + nq) * 64 + 32 + quad * 8);
      ffrag4 zv = {0.f, 0.f, 0.f, 0.f};
      zv = __builtin_amdgcn_mfma_f32_16x16x32_bf16(a0, bv0, zv, 0, 0, 0);
      zv = __builtin_amdgcn_mfma_f32_16x16x32_bf16(a1, bv1, zv, 0, 0, 0);
      int d = dt * 16 + c;
      #pragma unroll
      for (int r = 0; r < 4; ++r) {
        int i = i0 + quad * 4 + r;
        qs[i * 64 + ((((d >> 3) ^ (i & 7))) << 3) + (d & 7)] = f2b(zq[r] * sf[dt]);
        vt[d * VP + i] = f2b(zv[r]);
      }
    }
  }
  __syncthreads();

  uint16_t* pw = &pb[w][0];
  for (int it = w; it < 15; it += 4) {
    int i0 = it * 16;
    int ra = i0 + c, sa = ra & 7;
    bfrag8 a0 = *(const bfrag8*)(qs + ra * 64 + ((quad ^ sa) << 3));
    bfrag8 a1 = *(const bfrag8*)(qs + ra * 64 + (((quad + 4) ^ sa) << 3));
    ffrag4 acc[15];
    #pragma unroll
    for (int jt = 0; jt < 15; ++jt) {
      int rb = jt * 16 + c, sk = rb & 7;
      bfrag8 b0 = *(const bfrag8*)(qs + rb * 64 + ((quad ^ sk) << 3));
      bfrag8 b1 = *(const bfrag8*)(qs + rb * 64 + (((quad + 4) ^ sk) << 3));
      ffrag4 z = {0.f, 0.f, 0.f, 0.f};
      z = __builtin_amdgcn_mfma_f32_16x16x32_bf16(a0, b0, z, 0, 0, 0);
      z = __builtin_amdgcn_mfma_f32_16x16x32_bf16(a1, b1, z, 0, 0, 0);
      acc[jt] = z;
    }
    // softmax: store raw E = exp(S - m); 1/l applied at O store
    float rinv[4];
    #pragma unroll
    for (int r = 0; r < 4; ++r) {
      float m = -1e30f;
      #pragma unroll
      for (int jt = 0; jt < 15; ++jt) m = fmaxf(m, acc[jt][r]);
      #pragma unroll
      for (int o = 8; o; o >>= 1) m = fmaxf(m, __shfl_xor(m, o));
      float s = 0.f;
      #pragma unroll
      for (int jt = 0; jt < 15; ++jt) {
        float p = __expf(acc[jt][r] - m);
        if (jt == 14 && c >= 2) p = 0.f;   // j = 224+c >= 226 invalid (dup rows)
        acc[jt][r] = p;
        s += p;
      }
      #pragma unroll
      for (int o = 8; o; o >>= 1) s += __shfl_xor(s, o);
      rinv[r] = 1.f / s;
    }
    ffrag4 oa[4];
    #pragma unroll
    for (int dt = 0; dt < 4; ++dt) oa[dt] = (ffrag4){0.f, 0.f, 0.f, 0.f};
    for (int jc = 0; jc < 8; ++jc) {
      if (jc == 7) {
        *(uint64_t*)(pw + c * 32 + 16 + quad * 4) = 0ull;   // zero E cols 16..31
      }
      #pragma unroll
      for (int r = 0; r < 4; ++r) {
        int row = quad * 4 + r;
        pw[row * 32 + c] = f2b(acc[2 * jc][r]);
        if (jc < 7) pw[row * 32 + 16 + c] = f2b(acc[2 * jc + 1][r]);
      }
      bfrag8 pa = *(const bfrag8*)(pw + c * 32 + quad * 8);
      int j0 = jc * 32;
      #pragma unroll
      for (int dt = 0; dt < 4; ++dt) {
        bfrag8 vb;
        if (jc < 7)
          vb = *(const bfrag8*)(vt + (dt * 16 + c) * VP + j0 + quad * 8);
        else
          vb = *(const bfrag8*)(vt + (dt * 16 + c) * VP + 224 + (quad & 1) * 8);
        oa[dt] = __builtin_amdgcn_mfma_f32_16x16x32_bf16(pa, vb, oa[dt], 0, 0, 0);
      }
    }
    #pragma unroll
    for (int dt = 0; dt < 4; ++dt) {
      #pragma unroll
      for (int r = 0; r < 4; ++r) {
        int i = i0 + quad * 4 + r;
        if (i < NTOK)
          Og[((size_t)sb * NTOK + i) * NIN + h * DH + dt * 16 + c] =
              f2b(oa[dt][r] * rinv[r]);
      }
    }
  }
  // zero vt pad cols for NEXT use is not needed: vt zero loop below runs pre-sync
}

// ---- merged proj+FF: X += O@Wo+bo; LN2 (LDS); FF + residual; LN1-next ----
// Per-wave-exclusive 16-row tiles -> zero barriers. LDS = 9216 + 33792 = 43008 B.
__global__ __launch_bounds__(256) void k_pf(const uint16_t* __restrict__ Og,
    const uint16_t* __restrict__ Wot,   // [64][512] bf16
    const float* __restrict__ bo, float* __restrict__ X,
    const float* __restrict__ g2, const float* __restrict__ bb2,
    const uint16_t* __restrict__ W1t,   // [256][64] bf16
    const float* __restrict__ b1,
    const uint16_t* __restrict__ W2t,   // [64][256] bf16
    const float* __restrict__ b2,
    const float* __restrict__ gn, const float* __restrict__ bbn,
    uint16_t* __restrict__ XnOut) {
  __shared__ __align__(16) uint16_t xa2[64 * 72];      // 9216 B (pitch 72: even banks)
  __shared__ __align__(16) uint16_t ha[4][16 * 264];   // 33792 B per-wave h-tiles
  int t = threadIdx.x, w = t >> 6, l = t & 63;
  int quad = l >> 4, c = l & 15;
  int r0 = blockIdx.x * 64;

  // ---- proj part (R5 k_proj, verbatim) ----
  const uint16_t* orow = Og + (size_t)(r0 + w * 16 + c) * 512 + quad * 8;
  bfrag8 a[16];
  #pragma unroll
  for (int kc = 0; kc < 16; ++kc) a[kc] = *(const bfrag8*)(orow + kc * 32);
  ffrag4 acc[4];
  #pragma unroll
  for (int jt = 0; jt < 4; ++jt) acc[jt] = (ffrag4){0.f, 0.f, 0.f, 0.f};
  #pragma unroll
  for (int kc = 0; kc < 16; ++kc) {
    #pragma unroll
    for (int jt = 0; jt < 4; ++jt) {
      bfrag8 b = *(const bfrag8*)(Wot + (size_t)(jt * 16 + c) * 512 + kc * 32 + quad * 8);
      acc[jt] = __builtin_amdgcn_mfma_f32_16x16x32_bf16(a[kc], b, acc[jt], 0, 0, 0);
    }
  }
  float xv[4][4];
  #pragma unroll
  for (int jt = 0; jt < 4; ++jt) {
    float bv = bo[jt * 16 + c];
    #pragma unroll
    for (int r = 0; r < 4; ++r) {
      int il = w * 16 + quad * 4 + r;
      size_t idx = (size_t)(r0 + il) * 64 + jt * 16 + c;
      float v = X[idx] + acc[jt][r] + bv;
      X[idx] = v;
      xv[jt][r] = v;
    }
  }
  // LN2 -> xa2 (per-wave rows; no barrier needed)
  #pragma unroll
  for (int r = 0; r < 4; ++r) {
    float s = xv[0][r] + xv[1][r] + xv[2][r] + xv[3][r];
    float q = xv[0][r]*xv[0][r] + xv[1][r]*xv[1][r] + xv[2][r]*xv[2][r] + xv[3][r]*xv[3][r];
    #pragma unroll
    for (int o = 8; o; o >>= 1) { s += __shfl_xor(s, o); q += __shfl_xor(q, o); }
    float m = s * (1.f / 64.f);
    float rs = rsqrtf(q * (1.f / 64.f) - m * m + 1e-5f);
    int il = w * 16 + quad * 4 + r;
    #pragma unroll
    for (int jt = 0; jt < 4; ++jt) {
      int n = jt * 16 + c;
      xa2[il * 72 + n] = f2b((xv[jt][r] - m) * rs * g2[n] + bb2[n]);
    }
  }
  // ---- FF part (R5 k_ff with A from LDS xa2) ----
  const uint16_t* xrow = xa2 + (w * 16 + c) * 72;
  bfrag8 a0 = *(const bfrag8*)(xrow + quad * 8);
  bfrag8 a1 = *(const bfrag8*)(xrow + 32 + quad * 8);
  ffrag4 acc1[16];
  #pragma unroll
  for (int jt = 0; jt < 16; ++jt) {
    bfrag8 b0  = *(const bfrag8*)(W1t + (size_t)(jt * 16 + c) * 64 + quad * 8);
    bfrag8 b1f = *(const bfrag8*)(W1t + (size_t)(jt * 16 + c) * 64 + 32 + quad * 8);
    ffrag4 z = {0.f, 0.f, 0.f, 0.f};
    z = __builtin_amdgcn_mfma_f32_16x16x32_bf16(a0, b0, z, 0, 0, 0);
    z = __builtin_amdgcn_mfma_f32_16x16x32_bf16(a1, b1f, z, 0, 0, 0);
    acc1[jt] = z;
  }
  uint16_t* haw = &ha[w][0];
  #pragma unroll
  for (int jt = 0; jt < 16; ++jt) {
    float bv = b1[jt * 16 + c];
    #pragma unroll
    for (int r = 0; r < 4; ++r) {
      float z = acc1[jt][r] + bv;
      float hg = 0.5f * z * (1.f + erff(z * 0.7071067811865476f));
      haw[(quad * 4 + r) * 264 + jt * 16 + c] = f2b(hg);
    }
  }
  ffrag4 o2[4];
  #pragma unroll
  for (int jt = 0; jt < 4; ++jt) o2[jt] = (ffrag4){0.f, 0.f, 0.f, 0.f};
  #pragma unroll
  for (int kc = 0; kc < 8; ++kc) {
    bfrag8 pa = *(const bfrag8*)(haw + c * 264 + kc * 32 + quad * 8);
    #pragma unroll
    for (int jt = 0; jt < 4; ++jt) {
      bfrag8 vb = *(const bfrag8*)(W2t + (size_t)(jt * 16 + c) * 256 + kc * 32 + quad * 8);
      o2[jt] = __builtin_amdgcn_mfma_f32_16x16x32_bf16(pa, vb, o2[jt], 0, 0, 0);
    }
  }
  float yv[4][4];
  #pragma unroll
  for (int jt = 0; jt < 4; ++jt) {
    float bv = b2[jt * 16 + c];
    #pragma unroll
    for (int r = 0; r < 4; ++r) {
      int il = w * 16 + quad * 4 + r;
      size_t idx = (size_t)(r0 + il) * 64 + jt * 16 + c;
      float v = X[idx] + o2[jt][r] + bv;
      X[idx] = v;
      yv[jt][r] = v;
    }
  }
  #pragma unroll
  for (int r = 0; r < 4; ++r) {
    float s = yv[0][r] + yv[1][r] + yv[2][r] + yv[3][r];
    float q = yv[0][r]*yv[0][r] + yv[1][r]*yv[1][r] + yv[2][r]*yv[2][r] + yv[3][r]*yv[3][r];
    #pragma unroll
    for (int o = 8; o; o >>= 1) { s += __shfl_xor(s, o); q += __shfl_xor(q, o); }
    float m = s * (1.f / 64.f);
    float rs = rsqrtf(q * (1.f / 64.f) - m * m + 1e-5f);
    int il = w * 16 + quad * 4 + r;
    #pragma unroll
    for (int jt = 0; jt < 4; ++jt) {
      int n = jt * 16 + c;
      XnOut[(size_t)(r0 + il) * 64 + n] = f2b((yv[jt][r] - m) * rs * gn[n] + bbn[n]);
    }
  }
}

// ---- swap cls tokens between streams; refresh Xn (LN1 layer0) for those rows ----
__global__ void k_xchg(float* __restrict__ X, uint16_t* __restrict__ Xn,
                       const float* __restrict__ g, const float* __restrict__ bb) {
  int b = blockIdx.x, d = threadIdx.x;   // 64 blocks x 64 threads (1 wave)
  size_t i0 = (size_t)(b * NTOK) * ND + d;
  size_t i1 = (size_t)((64 + b) * NTOK) * ND + d;
  float a = X[i0], cc = X[i1];
  X[i0] = cc; X[i1] = a;
  float s0 = cc, q0 = cc * cc, s1 = a, q1 = a * a;
  #pragma unroll
  for (int o = 32; o; o >>= 1) {
    s0 += __shfl_xor(s0, o); q0 += __shfl_xor(q0, o);
    s1 += __shfl_xor(s1, o); q1 += __shfl_xor(q1, o);
  }
  float m0 = s0 * (1.f / 64.f), rs0 = rsqrtf(q0 * (1.f / 64.f) - m0 * m0 + 1e-5f);
  float m1 = s1 * (1.f / 64.f), rs1 = rsqrtf(q1 * (1.f / 64.f) - m1 * m1 + 1e-5f);
  Xn[i0] = f2b((cc - m0) * rs0 * g[d] + bb[d]);
  Xn[i1] = f2b((a - m1) * rs1 * g[d] + bb[d]);
}

// ---- final: out = h_cls + l_cls ----
__global__ void k_out(const float* __restrict__ X, float* __restrict__ out) {
  int i = blockIdx.x * 64 + threadIdx.x;
  int b = i >> 6, d = i & 63;
  out[i] = X[(size_t)b * NTOK * ND + d] + X[(size_t)(64 + b) * NTOK * ND + d];
}

extern "C" void kernel_launch(void* const* d_in, const int* in_sizes, int n_in,
                              void* d_out, int out_size, void* d_ws, size_t ws_size,
                              hipStream_t stream) {
  const float* hsi   = (const float*)d_in[0];
  const float* lidar = (const float*)d_in[1];
  const float* cls_h = (const float*)d_in[2];
  const float* cls_l = (const float*)d_in[3];
  const float* pos_h = (const float*)d_in[4];
  const float* pos_l = (const float*)d_in[5];
  const float* fmg_w = (const float*)d_in[6];
  const float* ln1_g = (const float*)d_in[7];
  const float* ln1_b = (const float*)d_in[8];
  const float* qkv_w = (const float*)d_in[9];
  const float* out_w = (const float*)d_in[10];
  const float* out_b = (const float*)d_in[11];
  const float* ln2_g = (const float*)d_in[12];
  const float* ln2_b = (const float*)d_in[13];
  const float* ff_w1 = (const float*)d_in[14];
  const float* ff_b1 = (const float*)d_in[15];
  const float* ff_w2 = (const float*)d_in[16];
  const float* ff_b2 = (const float*)d_in[17];

  char* ws = (char*)d_ws;
  float*    X    = (float*)ws;                       // 7,405,568 B
  float*    sdfm = (float*)(ws + 7405568);           // 16,384 B
  uint16_t* Xn   = (uint16_t*)(ws + 7421952);        // 3,702,784 B
  uint16_t* Og   = (uint16_t*)(ws + 11124736);       // 29,622,272 B
  uint16_t* Wqv  = (uint16_t*)(ws + 40747008);       // 524,288 B
  uint16_t* Wo   = (uint16_t*)(ws + 41271296);       // 262,144 B
  uint16_t* W1   = (uint16_t*)(ws + 41533440);       // 131,072 B
  uint16_t* W2   = (uint16_t*)(ws + 41664512);       // 131,072 B -> end 41,795,584

  k_wconv<<<2048, 256, 0, stream>>>(qkv_w, out_w, ff_w1, ff_w2, Wqv, Wo, W1, W2);
  k_dfm<<<NB, 128, 0, stream>>>(hsi, lidar, fmg_w, sdfm);
  k_build<<<NROWS, 64, 0, stream>>>(hsi, cls_h, cls_l, pos_h, pos_l,
                                    ln1_g, ln1_b, X, Xn);
  for (int pass = 0; pass < 2; ++pass) {
    for (int ly = 0; ly < NDEPTH; ++ly) {
      int nx = (ly + 1) & 3;   // next layer's LN1 params (harmless on final layer)
      k_fattn<<<NSB * NH, 256, 0, stream>>>(Xn, Wqv + (size_t)ly * 65536, sdfm, Og);
      k_pf<<<452, 256, 0, stream>>>(Og, Wo + (size_t)ly * 32768, out_b + ly * ND,
                                    X, ln2_g + ly * ND, ln2_b + ly * ND,
                                    W1 + (size_t)ly * 16384, ff_b1 + ly * NMLP,
                                    W2 + (size_t)ly * 16384, ff_b2 + ly * ND,
                                    ln1_g + nx * ND, ln1_b + nx * ND, Xn);
    }
    if (pass == 0) k_xchg<<<64, 64, 0, stream>>>(X, Xn, ln1_g, ln1_b);
  }
  k_out<<<64, 64, 0, stream>>>(X, (float*)d_out);
}